// Round 3
// baseline (90.220 us; speedup 1.0000x reference)
//
#include <hip/hip_runtime.h>
#include <math.h>

// Problem dims (fixed by setup_inputs): B=16, Cin=Cout=64, L=65536, M=512, Lh=32769
#define B_   16
#define CIN  64
#define COUT 64
#define L_   65536
#define M_   512
#define LH_  32769

#define NBLK     2048
#define NTHREADS (NBLK * 256)              // 524288
#define N4       ((B_ * COUT * LH_) / 4)   // 8388864 float4s = whole output

// Unaligned-safe float4 load/store (4B-aligned dwordx4 is fine on CDNA).
__device__ __forceinline__ float4 ld4u(const float* p) {
    float4 v; __builtin_memcpy(&v, p, sizeof(float4)); return v;
}
__device__ __forceinline__ void st4u(float* p, float4 v) {
    __builtin_memcpy(p, &v, sizeof(float4));
}

// ---------------------------------------------------------------------------
// Fused kernel.
// Part 1 (all threads): zero-fill output cols >= 512 (132 MB) — store-bound.
// Part 2 (wave 0 of even blocks, 65536 threads): each thread computes a
// 4m x 2o output tile for one b:
//   m2 = (512 - m) % 512
//   out[b,o,m] = 0.5*c2[m]/Cin * sum_i( x[b,i,m]*c1[m]*(w[i,o,m]+w[i,o,m2])
//                                     + x[b,i,m2]*c1[m2]*(w[i,o,m]-w[i,o,m2]) )
// Reversed (m2) runs are fetched as one float4 at 509-m0, consumed reversed;
// the m0==0 tile wraps at index 0 and takes a small fixup path.
// Part-1 and part-2 stores are disjoint (col>=512 vs col<512) -> no race.
// ---------------------------------------------------------------------------
__global__ __launch_bounds__(256) void fused_spectral(
    const float* __restrict__ x, const float* __restrict__ w, float* __restrict__ out)
{
    const int tid = blockIdx.x * 256 + threadIdx.x;

    // ---- Part 1: streaming zero-fill of the col>=512 region
    for (int j = tid; j < N4; j += NTHREADS) {
        const unsigned flat = (unsigned)j * 4u;
        const unsigned row  = flat / (unsigned)LH_;           // magic-mul
        const unsigned col  = flat - row * (unsigned)LH_;
        if (col >= (unsigned)M_ && col <= (unsigned)(LH_ - 4)) {
            const float4 z = {0.f, 0.f, 0.f, 0.f};
            reinterpret_cast<float4*>(out)[j] = z;
        } else {
            #pragma unroll
            for (int e = 0; e < 4; ++e) {
                const unsigned f  = flat + (unsigned)e;
                const unsigned r2 = f / (unsigned)LH_;
                const unsigned c2_ = f - r2 * (unsigned)LH_;
                if (c2_ >= (unsigned)M_) out[f] = 0.f;
            }
        }
    }

    // ---- Part 2: compute region — wave 0 of even blocks
    if ((blockIdx.x & 1) || threadIdx.x >= 64) return;
    const int ctid = (int)(blockIdx.x >> 1) * 64 + (int)threadIdx.x; // 0..65535
    const int mg = ctid & 127;          // m-group: m0 = mg*4 (lanes -> coalesced)
    const int op = (ctid >> 7) & 31;    // o-pair:  o0 = op*2
    const int b  = ctid >> 12;          // 0..15
    const int m0 = mg * 4;
    const int o0 = op * 2;
    const int roff = mg ? (509 - m0) : 508;   // reversed-run float4 base

    const float TWO_PI = 6.28318530717958647692f;
    float c1m[4], c1n[4], c2v[4];
    #pragma unroll
    for (int e = 0; e < 4; ++e) {
        const int m  = m0 + e;
        const int m2 = (M_ - m) & (M_ - 1);
        const float t1  = TWO_PI * (float)m  / (float)L_;
        const float t1n = TWO_PI * (float)m2 / (float)L_;
        const float t2  = TWO_PI * (float)m  / (float)LH_;
        c1m[e] = cosf(t1)  - sinf(t1);
        c1n[e] = cosf(t1n) - sinf(t1n);
        c2v[e] = (cosf(t2) - sinf(t2)) * (0.5f / (float)CIN);
    }

    float acc0[4] = {0.f,0.f,0.f,0.f};
    float acc1[4] = {0.f,0.f,0.f,0.f};
    const float* xb = x + (size_t)b * CIN * L_;

    for (int i = 0; i < CIN; ++i) {
        const float* xr = xb + (size_t)i * L_;
        const float4 xf = ld4u(xr + m0);
        const float4 xl = ld4u(xr + roff);
        float xm[4], xn[4];
        xm[0] = xf.x * c1m[0]; xm[1] = xf.y * c1m[1];
        xm[2] = xf.z * c1m[2]; xm[3] = xf.w * c1m[3];
        float r0, r1, r2, r3;
        if (mg) { r0 = xl.w; r1 = xl.z; r2 = xl.y; r3 = xl.x; }
        else    { r0 = xr[0]; r1 = xl.w; r2 = xl.z; r3 = xl.y; }
        xn[0] = r0 * c1n[0]; xn[1] = r1 * c1n[1];
        xn[2] = r2 * c1n[2]; xn[3] = r3 * c1n[3];

        const float* wi = w + (size_t)(i * COUT + o0) * M_;
        #pragma unroll
        for (int oo = 0; oo < 2; ++oo) {
            const float* wr = wi + (size_t)oo * M_;
            const float4 wf = ld4u(wr + m0);
            const float4 wl = ld4u(wr + roff);
            float n0, n1, n2, n3;
            if (mg) { n0 = wl.w; n1 = wl.z; n2 = wl.y; n3 = wl.x; }
            else    { n0 = wr[0]; n1 = wl.w; n2 = wl.z; n3 = wl.y; }
            float* acc = oo ? acc1 : acc0;
            acc[0] += xm[0] * (wf.x + n0) + xn[0] * (wf.x - n0);
            acc[1] += xm[1] * (wf.y + n1) + xn[1] * (wf.y - n1);
            acc[2] += xm[2] * (wf.z + n2) + xn[2] * (wf.z - n2);
            acc[3] += xm[3] * (wf.w + n3) + xn[3] * (wf.w - n3);
        }
    }

    #pragma unroll
    for (int oo = 0; oo < 2; ++oo) {
        float* acc = oo ? acc1 : acc0;
        float4 r;
        r.x = acc[0] * c2v[0]; r.y = acc[1] * c2v[1];
        r.z = acc[2] * c2v[2]; r.w = acc[3] * c2v[3];
        st4u(out + (size_t)(b * COUT + o0 + oo) * LH_ + m0, r);
    }
}

extern "C" void kernel_launch(void* const* d_in, const int* in_sizes, int n_in,
                              void* d_out, int out_size, void* d_ws, size_t ws_size,
                              hipStream_t stream) {
    const float* x = (const float*)d_in[0];   // (16, 64, 65536) f32
    const float* w = (const float*)d_in[1];   // (64, 64, 512)   f32
    float* out = (float*)d_out;               // (16, 64, 32769) f32

    fused_spectral<<<NBLK, 256, 0, stream>>>(x, w, out);
}

// Round 4
// 70.886 us; speedup vs baseline: 1.2727x; 1.2727x over previous
//
#include <hip/hip_runtime.h>
#include <math.h>

// Problem dims (fixed by setup_inputs): B=16, Cin=Cout=64, L=65536, M=512, Lh=32769
#define B_   16
#define CIN  64
#define COUT 64
#define L_   65536
#define M_   512
#define LH_  32769

#define NBLK       2048
#define N4         ((B_ * COUT * LH_) / 4)  // 8388864 float4s = whole output
#define NWAVES     (NBLK * 4)               // 8192
#define NCOMPWAVES 1024                     // gw % 8 == 0
#define NFILLTHREADS ((NWAVES - NCOMPWAVES) * 64)  // 458752

// ---------------------------------------------------------------------------
// Fused kernel, wave-specialized:
//  - Compute waves (gw%8==0, 1024 waves): only compute cols [0,512).
//      Thread tile: 4b x 2o at one m.  m = lane-contiguous -> all loads are
//      coalesced scalar dwords.  12 loads / 32 fma-flops per i-iter.
//  - Fill waves (7168 waves): only zero-fill cols >= 512 (132 MB, store-bound).
//  Stores disjoint (col<512 vs col>=512) -> no race.
//
//   m2 = (512 - m) % 512
//   out[b,o,m] = 0.5*c2[m] * sum_i( x[b,i,m]*c1[m]*(w[i,o,m]+w[i,o,m2])
//                                 + x[b,i,m2]*c1[m2]*(w[i,o,m]-w[i,o,m2]) )
//   c1[m] = cos(2pi m/L) - sin(2pi m/L);  c2[m] = (cos(2pi m/Lh)-sin(2pi m/Lh))/Cin
// ---------------------------------------------------------------------------
__global__ __launch_bounds__(256) void fused_spectral(
    const float* __restrict__ x, const float* __restrict__ w, float* __restrict__ out)
{
    const int wv   = (int)threadIdx.x >> 6;
    const int lane = (int)threadIdx.x & 63;
    const int gw   = (int)blockIdx.x * 4 + wv;      // global wave id, 0..8191

    if ((gw & 7) == 0) {
        // ---- Compute wave ----
        const int cw = gw >> 3;                     // 0..1023
        const int m  = ((cw & 7) << 6) + lane;      // 0..511, lane-contiguous
        const int o0 = ((cw >> 3) & 31) * 2;        // o pair
        const int b0 = (cw >> 8) * 4;               // b quad
        const int m2 = (M_ - m) & (M_ - 1);

        const float TWO_PI = 6.28318530717958647692f;
        const float t1  = TWO_PI * (float)m  / (float)L_;
        const float t1n = TWO_PI * (float)m2 / (float)L_;
        const float t2  = TWO_PI * (float)m  / (float)LH_;
        const float c1m = cosf(t1)  - sinf(t1);
        const float c1n = cosf(t1n) - sinf(t1n);
        const float c2  = (cosf(t2) - sinf(t2)) * (0.5f / (float)CIN);

        float acc[4][2];
        #pragma unroll
        for (int bb = 0; bb < 4; ++bb) { acc[bb][0] = 0.f; acc[bb][1] = 0.f; }

        const float* xb0 = x + (size_t)(b0 + 0) * CIN * L_;
        const float* xb1 = x + (size_t)(b0 + 1) * CIN * L_;
        const float* xb2 = x + (size_t)(b0 + 2) * CIN * L_;
        const float* xb3 = x + (size_t)(b0 + 3) * CIN * L_;

        #pragma unroll 4
        for (int i = 0; i < CIN; ++i) {
            const size_t ro = (size_t)i * L_;
            const float xm0 = xb0[ro + m] * c1m, xn0 = xb0[ro + m2] * c1n;
            const float xm1 = xb1[ro + m] * c1m, xn1 = xb1[ro + m2] * c1n;
            const float xm2v = xb2[ro + m] * c1m, xn2v = xb2[ro + m2] * c1n;
            const float xm3 = xb3[ro + m] * c1m, xn3 = xb3[ro + m2] * c1n;

            const float* wr = w + (size_t)(i * COUT + o0) * M_;
            const float wm0 = wr[m],      wn0 = wr[m2];
            const float wm1 = wr[M_ + m], wn1 = wr[M_ + m2];
            const float ws0 = wm0 + wn0, wd0 = wm0 - wn0;
            const float ws1 = wm1 + wn1, wd1 = wm1 - wn1;

            acc[0][0] += xm0 * ws0 + xn0 * wd0;
            acc[1][0] += xm1 * ws0 + xn1 * wd0;
            acc[2][0] += xm2v * ws0 + xn2v * wd0;
            acc[3][0] += xm3 * ws0 + xn3 * wd0;
            acc[0][1] += xm0 * ws1 + xn0 * wd1;
            acc[1][1] += xm1 * ws1 + xn1 * wd1;
            acc[2][1] += xm2v * ws1 + xn2v * wd1;
            acc[3][1] += xm3 * ws1 + xn3 * wd1;
        }

        #pragma unroll
        for (int bb = 0; bb < 4; ++bb)
            #pragma unroll
            for (int oo = 0; oo < 2; ++oo)
                out[(size_t)((b0 + bb) * COUT + o0 + oo) * LH_ + m] = c2 * acc[bb][oo];
        return;
    }

    // ---- Fill wave: zero-fill the col>=512 region ----
    const int fwave = gw - ((gw + 7) >> 3);         // dense index over fill waves
    const int ft = fwave * 64 + lane;
    for (int j = ft; j < N4; j += NFILLTHREADS) {
        const unsigned flat = (unsigned)j * 4u;
        const unsigned row  = flat / (unsigned)LH_;  // magic-mul, const divisor
        const unsigned col  = flat - row * (unsigned)LH_;
        if (col >= (unsigned)M_ && col <= (unsigned)(LH_ - 4)) {
            const float4 z = {0.f, 0.f, 0.f, 0.f};
            reinterpret_cast<float4*>(out)[j] = z;
        } else {
            #pragma unroll
            for (int e = 0; e < 4; ++e) {
                const unsigned f  = flat + (unsigned)e;
                const unsigned r2 = f / (unsigned)LH_;
                const unsigned c2_ = f - r2 * (unsigned)LH_;
                if (c2_ >= (unsigned)M_) out[f] = 0.f;
            }
        }
    }
}

extern "C" void kernel_launch(void* const* d_in, const int* in_sizes, int n_in,
                              void* d_out, int out_size, void* d_ws, size_t ws_size,
                              hipStream_t stream) {
    const float* x = (const float*)d_in[0];   // (16, 64, 65536) f32
    const float* w = (const float*)d_in[1];   // (64, 64, 512)   f32
    float* out = (float*)d_out;               // (16, 64, 32769) f32

    fused_spectral<<<NBLK, 256, 0, stream>>>(x, w, out);
}